// Round 3
// baseline (261.166 us; speedup 1.0000x reference)
//
#include <hip/hip_runtime.h>

// Problem constants
#define B_    16
#define N_    1024
#define DIN_  256
#define H_    4
#define F_    64
#define COUT_ 256
#define NEG_  0.2f
#define LOG2E_ 1.4426950408889634f

typedef __bf16 bf16x8 __attribute__((ext_vector_type(8)));
typedef float  f32x4  __attribute__((ext_vector_type(4)));
typedef unsigned short u16x8 __attribute__((ext_vector_type(8)));
typedef unsigned short u16x4 __attribute__((ext_vector_type(4)));
typedef unsigned int   u32x4 __attribute__((ext_vector_type(4)));

__device__ __forceinline__ unsigned short f2bf(float f) {
    unsigned u = __builtin_bit_cast(unsigned, f);
    u += 0x7fffu + ((u >> 16) & 1u);
    return (unsigned short)(u >> 16);
}

// ---------------------------------------------------------------------------
// Prep: pack W into MFMA-B-frag order Wtp, bf16 (1KB-contiguous frag loads).
// Element (c,k): w=c>>6, ft=(c>>4)&3, l15=c&15, it=k>>5, q=(k>>3)&3, jj=k&7,
// ln=q*16+l15 -> Wtp[(((w*8+it)*4+ft)*64 + ln)*8 + jj].   [R5-proven]
// ---------------------------------------------------------------------------
__global__ __launch_bounds__(256) void prep_kernel(
    const float* __restrict__ W, unsigned short* __restrict__ Wtp) {
    const int c = blockIdx.x, k = threadIdx.x;
    const int w = c >> 6, ft = (c >> 4) & 3, l15 = c & 15;
    const int it = k >> 5, q = (k >> 3) & 3, jj = k & 7;
    const int ln = q * 16 + l15;
    Wtp[((((w * 8 + it) * 4 + ft) * 64) + ln) * 8 + jj] = f2bf(W[k * COUT_ + c]);
}

// ---------------------------------------------------------------------------
// Stage kernel (R1-proven structure, restored: R2's adj fusion into attn was
// a 16-row gather pattern -> latency-bound, +12us. Coalesced masker wins.)
// Part 1 (blocks 0..4095): adj -> transposed bitmask, COALESCED: one adj
//   row per wave (f32x4/lane x 4 chunks, contiguous 1KB/inst), nibble build
//   + 3x shfl_xor OR-reduce within 8-lane groups, (ln&7)==0 lanes store.
// Part 2 (blocks 4096..5119): h = x @ W via bf16 MFMA (R5 numerics) with x
//   staged through LDS. hp frag-packed [b][h][jg][ft][ln][8]; e logits
//   (x log2e) from fp32 acc, stored f32.
// ---------------------------------------------------------------------------
__global__ __launch_bounds__(256, 4) void stage_kernel(
    const float* __restrict__ adj, const float* __restrict__ x,
    const unsigned short* __restrict__ Wtp, const float* __restrict__ a_src,
    const float* __restrict__ a_dst, unsigned int* __restrict__ mask,
    unsigned short* __restrict__ hp, float* __restrict__ e_src,
    float* __restrict__ e_dst) {
    __shared__ unsigned short xs[16][264];   // bf16 bits; padded row stride
    const int w  = threadIdx.x >> 6;
    const int ln = threadIdx.x & 63;

    if (blockIdx.x < 4096) {
        // ---- masker part: 1 row per wave, fully coalesced ----
        const int row = blockIdx.x * 4 + w;          // b*N + i, 0..16383
        const int b = row >> 10, i = row & (N_ - 1);
        const float* ar = adj + (size_t)row * N_ + ln * 4;
#pragma unroll
        for (int c = 0; c < 4; c++) {
            f32x4 v = *(const f32x4*)(ar + c * 256);
            unsigned nib = 0;
#pragma unroll
            for (int e = 0; e < 4; e++)
                nib |= (v[e] > 0.5f) ? (1u << e) : 0u;
            // lane ln covers cols c*256 + ln*4 .. +3 -> word bit (ln&7)*4+e
            unsigned word = nib << ((ln & 7) * 4);
            word |= __shfl_xor(word, 1);
            word |= __shfl_xor(word, 2);
            word |= __shfl_xor(word, 4);
            if ((ln & 7) == 0) {
                const int jc = c * 8 + (ln >> 3);
                mask[(b * 32 + jc) * N_ + i] = word;
            }
        }
    } else {
        // ---- gat_h part (bf16, R5 numerics, LDS-staged x) ----
        const int blk = blockIdx.x - 4096;
        const int b   = blk & 15;
        const int it0 = (blk >> 4) * 16;
        const int l15 = ln & 15;
        const int q   = ln >> 4;

#pragma unroll
        for (int s = 0; s < 4; s++) {
            const int row = w * 4 + s;
            f32x4 xv = *(const f32x4*)(x + (size_t)(b * N_ + it0 + row) * DIN_ + ln * 4);
            unsigned lo = (unsigned)f2bf(xv[0]) | ((unsigned)f2bf(xv[1]) << 16);
            unsigned hi = (unsigned)f2bf(xv[2]) | ((unsigned)f2bf(xv[3]) << 16);
            unsigned long long hb = (unsigned long long)lo | ((unsigned long long)hi << 32);
            *(unsigned long long*)&xs[row][ln * 4] = hb;
        }
        __syncthreads();

        f32x4 acc[4];
#pragma unroll
        for (int ft = 0; ft < 4; ft++) acc[ft] = (f32x4)0.0f;

        const unsigned short* wb = Wtp + (w * 8) * 4 * 64 * 8 + ln * 8;
#pragma unroll
        for (int it = 0; it < 8; it++) {
            bf16x8 af = *(const bf16x8*)&xs[l15][it * 32 + q * 8];
#pragma unroll
            for (int ft = 0; ft < 4; ft++) {
                bf16x8 bf = *((const bf16x8*)(wb + (it * 4 + ft) * 512));
                acc[ft] = __builtin_amdgcn_mfma_f32_16x16x32_bf16(af, bf, acc[ft], 0, 0, 0);
            }
        }

        // Store hp frag-packed (R5 layout). Lane holds h[i=it0+q*4+r][f=ft*16+l15].
        const int jg = it0 >> 5;
        const int q2 = 2 * ((it0 >> 4) & 1) + (q >> 1);
#pragma unroll
        for (int ft = 0; ft < 4; ft++) {
            u16x4 hb;
#pragma unroll
            for (int r = 0; r < 4; r++) hb[r] = f2bf(acc[ft][r]);
            const size_t addr =
                (size_t)((((b * H_ + w) * 32 + jg) * 4 + ft) * 64 + q2 * 16 + l15) * 8 + (q & 1) * 4;
            *((u16x4*)(hp + addr)) = hb;
        }

        // e logits from fp32 acc (x log2e), stored f32 (R5 path).
        float as_v[4], ad_v[4];
#pragma unroll
        for (int ft = 0; ft < 4; ft++) {
            as_v[ft] = a_src[w * F_ + ft * 16 + l15];
            ad_v[ft] = a_dst[w * F_ + ft * 16 + l15];
        }
        float ps[4], pd[4];
#pragma unroll
        for (int r = 0; r < 4; r++) {
            ps[r] = 0.0f; pd[r] = 0.0f;
#pragma unroll
            for (int ft = 0; ft < 4; ft++) {
                ps[r] += acc[ft][r] * as_v[ft];
                pd[r] += acc[ft][r] * ad_v[ft];
            }
        }
#pragma unroll
        for (int off = 1; off <= 8; off <<= 1)
#pragma unroll
            for (int r = 0; r < 4; r++) {
                ps[r] += __shfl_xor(ps[r], off);
                pd[r] += __shfl_xor(pd[r], off);
            }
        float vs = (l15 == 0) ? ps[0] : (l15 == 1) ? ps[1] : (l15 == 2) ? ps[2] : ps[3];
        float vd = (l15 == 0) ? pd[0] : (l15 == 1) ? pd[1] : (l15 == 2) ? pd[2] : pd[3];
        if (l15 < 4) {
            const int i = it0 + q * 4 + l15;
            e_src[(b * H_ + w) * N_ + i] = vs * LOG2E_;
            e_dst[(b * H_ + w) * N_ + i] = vd * LOG2E_;
        }
    }
}

// ---------------------------------------------------------------------------
// Kernel C (R8): fused mask/leaky/exp2 + (P @ h) MFMA + normalize + bias.
// R5 numerics; R8 change: LATENCY/OCCUPANCY fix. R2 counters showed attn is
// latency-bound (Occupancy 33%, VALU 23%, MFMA 6.5%, HBM 11%). Old shape:
// 512-thr blocks (8 waves = 4h x 2 j-halves) -> only 16 waves/CU possible.
// New shape: 1024-thr blocks, 16 waves = 4 heads x 4 j-QUARTERS (8 jg each).
// 2 blocks/CU x 16 waves = 32 waves/CU (100% slots): LDS 40KB x2 = 80KB ok,
// __launch_bounds__(1024,8) caps VGPR at 64 (body measured 52). Combine is
// a sequential 4-pass add into one 40KB buffer (jq3 store, jq2/jq1 add,
// jq0 add + epilogue) - 3 extra syncs, ~30 DS ops, negligible.
// ---------------------------------------------------------------------------
__global__ __launch_bounds__(1024, 8) void gat_attn_kernel(
    const unsigned int* __restrict__ mask, const unsigned short* __restrict__ hp,
    const float* __restrict__ e_src, const float* __restrict__ e_dst,
    const float* __restrict__ bias, float* __restrict__ out) {
    const int lid = ((blockIdx.x & 7) << 6) | (blockIdx.x >> 3);  // XCD swizzle
    const int b   = lid >> 5;
    const int it0 = (lid & 31) * 32;
    const int w16 = threadIdx.x >> 6;
    const int h   = w16 & 3;            // head
    const int jq  = w16 >> 2;           // j-quarter (0..3)
    const int ln  = threadIdx.x & 63;
    const int l15 = ln & 15;
    const int q   = ln >> 4;

    __shared__ float lds[H_][2][5][64][4];   // 40 KB: acc[2][4] + accs[2]

    float edv[2];
    edv[0] = e_dst[(b * H_ + h) * N_ + it0 + l15];
    edv[1] = e_dst[(b * H_ + h) * N_ + it0 + 16 + l15];

    const float* es_base          = e_src + (b * H_ + h) * N_;
    const unsigned short* hp_base = hp + (size_t)((b * H_ + h) * 32) * 2048 + ln * 8;
    const unsigned int* mk0       = mask + b * 32 * N_ + it0;

    f32x4 acc[2][4];
    f32x4 accs[2];
#pragma unroll
    for (int mt = 0; mt < 2; mt++) {
#pragma unroll
        for (int ft = 0; ft < 4; ft++) acc[mt][ft] = (f32x4)0.0f;
        accs[mt] = (f32x4)0.0f;
    }

    u16x8 ones_u;
#pragma unroll
    for (int jj = 0; jj < 8; jj++) ones_u[jj] = 0x3F80;   // bf16 1.0
    const bf16x8 ones = __builtin_bit_cast(bf16x8, ones_u);

    for (int jg = jq * 8; jg < jq * 8 + 8; jg++) {
        const unsigned short* hf = hp_base + jg * 2048;
        bf16x8 bfr0 = *((const bf16x8*)(hf + 0 * 512));
        bf16x8 bfr1 = *((const bf16x8*)(hf + 1 * 512));
        bf16x8 bfr2 = *((const bf16x8*)(hf + 2 * 512));
        bf16x8 bfr3 = *((const bf16x8*)(hf + 3 * 512));
        f32x4 e0 = *(const f32x4*)(es_base + jg * 32 + q * 8);
        f32x4 e1 = *(const f32x4*)(es_base + jg * 32 + q * 8 + 4);
        const unsigned m0 = mk0[jg * N_ + l15];
        const unsigned m1 = mk0[jg * N_ + 16 + l15];

        float es8[8] = {e0[0], e0[1], e0[2], e0[3], e1[0], e1[1], e1[2], e1[3]};

        bf16x8 afr[2];
#pragma unroll
        for (int mt = 0; mt < 2; mt++) {
            const unsigned mq = ((mt ? m1 : m0) >> (q * 8)) & 0xffu;
            u32x4 up;
#pragma unroll
            for (int p2 = 0; p2 < 4; p2++) {
                float t0 = edv[mt] + es8[2 * p2];
                float t1 = edv[mt] + es8[2 * p2 + 1];
                t0 = fmaxf(t0, NEG_ * t0);                 // leaky (log2-space)
                t1 = fmaxf(t1, NEG_ * t1);
                float p0 = __builtin_amdgcn_exp2f(t0);
                float p1 = __builtin_amdgcn_exp2f(t1);
                p0 = ((mq >> (2 * p2)) & 1u) ? p0 : 0.0f;
                p1 = ((mq >> (2 * p2 + 1)) & 1u) ? p1 : 0.0f;
                up[p2] = __builtin_amdgcn_perm(__builtin_bit_cast(unsigned, p1),
                                               __builtin_bit_cast(unsigned, p0),
                                               0x07060302u);
            }
            afr[mt] = __builtin_bit_cast(bf16x8, up);
        }
#pragma unroll
        for (int mt = 0; mt < 2; mt++) {
            acc[mt][0] = __builtin_amdgcn_mfma_f32_16x16x32_bf16(afr[mt], bfr0, acc[mt][0], 0, 0, 0);
            acc[mt][1] = __builtin_amdgcn_mfma_f32_16x16x32_bf16(afr[mt], bfr1, acc[mt][1], 0, 0, 0);
            acc[mt][2] = __builtin_amdgcn_mfma_f32_16x16x32_bf16(afr[mt], bfr2, acc[mt][2], 0, 0, 0);
            acc[mt][3] = __builtin_amdgcn_mfma_f32_16x16x32_bf16(afr[mt], bfr3, acc[mt][3], 0, 0, 0);
            accs[mt]   = __builtin_amdgcn_mfma_f32_16x16x32_bf16(afr[mt], ones, accs[mt], 0, 0, 0);
        }
    }

    // 4-way sequential combine into one 40KB LDS buffer.
    if (jq == 3) {
#pragma unroll
        for (int mt = 0; mt < 2; mt++) {
#pragma unroll
            for (int ft = 0; ft < 4; ft++)
                *(f32x4*)&lds[h][mt][ft][ln][0] = acc[mt][ft];
            *(f32x4*)&lds[h][mt][4][ln][0] = accs[mt];
        }
    }
    __syncthreads();
    if (jq == 2) {
#pragma unroll
        for (int mt = 0; mt < 2; mt++) {
#pragma unroll
            for (int ft = 0; ft < 4; ft++) {
                f32x4 t = *(const f32x4*)&lds[h][mt][ft][ln][0];
                *(f32x4*)&lds[h][mt][ft][ln][0] = t + acc[mt][ft];
            }
            f32x4 ts = *(const f32x4*)&lds[h][mt][4][ln][0];
            *(f32x4*)&lds[h][mt][4][ln][0] = ts + accs[mt];
        }
    }
    __syncthreads();
    if (jq == 1) {
#pragma unroll
        for (int mt = 0; mt < 2; mt++) {
#pragma unroll
            for (int ft = 0; ft < 4; ft++) {
                f32x4 t = *(const f32x4*)&lds[h][mt][ft][ln][0];
                *(f32x4*)&lds[h][mt][ft][ln][0] = t + acc[mt][ft];
            }
            f32x4 ts = *(const f32x4*)&lds[h][mt][4][ln][0];
            *(f32x4*)&lds[h][mt][4][ln][0] = ts + accs[mt];
        }
    }
    __syncthreads();
    if (jq == 0) {
#pragma unroll
        for (int mt = 0; mt < 2; mt++) {
#pragma unroll
            for (int ft = 0; ft < 4; ft++)
                acc[mt][ft] += *(const f32x4*)&lds[h][mt][ft][ln][0];
            accs[mt] += *(const f32x4*)&lds[h][mt][4][ln][0];
        }
        float bias_v[4];
#pragma unroll
        for (int ft = 0; ft < 4; ft++) bias_v[ft] = bias[h * F_ + ft * 16 + l15];
#pragma unroll
        for (int mt = 0; mt < 2; mt++) {
            f32x4 rinv;
#pragma unroll
            for (int r = 0; r < 4; r++) rinv[r] = 1.0f / accs[mt][r];
#pragma unroll
            for (int ft = 0; ft < 4; ft++)
#pragma unroll
                for (int r = 0; r < 4; r++) {
                    const int i = it0 + mt * 16 + q * 4 + r;
                    const int c = h * F_ + ft * 16 + l15;
                    out[(size_t)(b * N_ + i) * COUT_ + c] = acc[mt][ft][r] * rinv[r] + bias_v[ft];
                }
        }
    }
}

// ---------------------------------------------------------------------------
// Workspace layout (bytes):
//   [0, 128K)    Wtp  bf16 frag-packed [256][256]
//   [128K, +8M)  hp   bf16 frag-packed [B][H][32][4][64][8]
//   +8M: e_src f32 (256K), e_dst f32 (256K), mask u32 (2M). Total ~10.7 MB.
// ---------------------------------------------------------------------------
extern "C" void kernel_launch(void* const* d_in, const int* in_sizes, int n_in,
                              void* d_out, int out_size, void* d_ws, size_t ws_size,
                              hipStream_t stream) {
    const float* x     = (const float*)d_in[0];
    const float* adj   = (const float*)d_in[1];
    const float* W     = (const float*)d_in[2];
    const float* a_src = (const float*)d_in[3];
    const float* a_dst = (const float*)d_in[4];
    const float* bias  = (const float*)d_in[5];
    float* out = (float*)d_out;

    char* ws = (char*)d_ws;
    unsigned short* Wtp = (unsigned short*)ws;
    unsigned short* hp  = (unsigned short*)(ws + 131072);
    float* e_src        = (float*)(ws + 131072 + 8388608);
    float* e_dst        = (float*)(ws + 131072 + 8388608 + 262144);
    unsigned int* mask  = (unsigned int*)(ws + 131072 + 8388608 + 524288);

    prep_kernel<<<256, 256, 0, stream>>>(W, Wtp);
    stage_kernel<<<5120, 256, 0, stream>>>(adj, x, Wtp, a_src, a_dst, mask, hp, e_src, e_dst);
    gat_attn_kernel<<<512, 1024, 0, stream>>>(mask, hp, e_src, e_dst, bias, out);
}

// Round 4
// 151.325 us; speedup vs baseline: 1.7259x; 1.7259x over previous
//
#include <hip/hip_runtime.h>

// Problem constants
#define B_    16
#define N_    1024
#define DIN_  256
#define H_    4
#define F_    64
#define COUT_ 256
#define NEG_  0.2f
#define LOG2E_ 1.4426950408889634f

typedef __bf16 bf16x8 __attribute__((ext_vector_type(8)));
typedef float  f32x4  __attribute__((ext_vector_type(4)));
typedef unsigned short u16x8 __attribute__((ext_vector_type(8)));
typedef unsigned short u16x4 __attribute__((ext_vector_type(4)));
typedef unsigned int   u32x4 __attribute__((ext_vector_type(4)));

__device__ __forceinline__ unsigned short f2bf(float f) {
    unsigned u = __builtin_bit_cast(unsigned, f);
    u += 0x7fffu + ((u >> 16) & 1u);
    return (unsigned short)(u >> 16);
}

// ---------------------------------------------------------------------------
// Prep: pack W into MFMA-B-frag order Wtp, bf16 (1KB-contiguous frag loads).
// Element (c,k): w=c>>6, ft=(c>>4)&3, l15=c&15, it=k>>5, q=(k>>3)&3, jj=k&7,
// ln=q*16+l15 -> Wtp[(((w*8+it)*4+ft)*64 + ln)*8 + jj].   [R5-proven]
// ---------------------------------------------------------------------------
__global__ __launch_bounds__(256) void prep_kernel(
    const float* __restrict__ W, unsigned short* __restrict__ Wtp) {
    const int c = blockIdx.x, k = threadIdx.x;
    const int w = c >> 6, ft = (c >> 4) & 3, l15 = c & 15;
    const int it = k >> 5, q = (k >> 3) & 3, jj = k & 7;
    const int ln = q * 16 + l15;
    Wtp[((((w * 8 + it) * 4 + ft) * 64) + ln) * 8 + jj] = f2bf(W[k * COUT_ + c]);
}

// ---------------------------------------------------------------------------
// Stage kernel (R0-proven, unchanged).
// Part 1 (blocks 0..4095): adj -> transposed bitmask, coalesced.
// Part 2 (blocks 4096..5119): h = x @ W via bf16 MFMA; hp frag-packed;
//   e logits (x log2e) from fp32 acc, stored f32.
// ---------------------------------------------------------------------------
__global__ __launch_bounds__(256, 4) void stage_kernel(
    const float* __restrict__ adj, const float* __restrict__ x,
    const unsigned short* __restrict__ Wtp, const float* __restrict__ a_src,
    const float* __restrict__ a_dst, unsigned int* __restrict__ mask,
    unsigned short* __restrict__ hp, float* __restrict__ e_src,
    float* __restrict__ e_dst) {
    __shared__ unsigned short xs[16][264];   // bf16 bits; padded row stride
    const int w  = threadIdx.x >> 6;
    const int ln = threadIdx.x & 63;

    if (blockIdx.x < 4096) {
        // ---- masker part: 1 row per wave, fully coalesced ----
        const int row = blockIdx.x * 4 + w;          // b*N + i, 0..16383
        const int b = row >> 10, i = row & (N_ - 1);
        const float* ar = adj + (size_t)row * N_ + ln * 4;
#pragma unroll
        for (int c = 0; c < 4; c++) {
            f32x4 v = *(const f32x4*)(ar + c * 256);
            unsigned nib = 0;
#pragma unroll
            for (int e = 0; e < 4; e++)
                nib |= (v[e] > 0.5f) ? (1u << e) : 0u;
            // lane ln covers cols c*256 + ln*4 .. +3 -> word bit (ln&7)*4+e
            unsigned word = nib << ((ln & 7) * 4);
            word |= __shfl_xor(word, 1);
            word |= __shfl_xor(word, 2);
            word |= __shfl_xor(word, 4);
            if ((ln & 7) == 0) {
                const int jc = c * 8 + (ln >> 3);
                mask[(b * 32 + jc) * N_ + i] = word;
            }
        }
    } else {
        // ---- gat_h part (bf16, R5 numerics, LDS-staged x) ----
        const int blk = blockIdx.x - 4096;
        const int b   = blk & 15;
        const int it0 = (blk >> 4) * 16;
        const int l15 = ln & 15;
        const int q   = ln >> 4;

#pragma unroll
        for (int s = 0; s < 4; s++) {
            const int row = w * 4 + s;
            f32x4 xv = *(const f32x4*)(x + (size_t)(b * N_ + it0 + row) * DIN_ + ln * 4);
            unsigned lo = (unsigned)f2bf(xv[0]) | ((unsigned)f2bf(xv[1]) << 16);
            unsigned hi = (unsigned)f2bf(xv[2]) | ((unsigned)f2bf(xv[3]) << 16);
            unsigned long long hb = (unsigned long long)lo | ((unsigned long long)hi << 32);
            *(unsigned long long*)&xs[row][ln * 4] = hb;
        }
        __syncthreads();

        f32x4 acc[4];
#pragma unroll
        for (int ft = 0; ft < 4; ft++) acc[ft] = (f32x4)0.0f;

        const unsigned short* wb = Wtp + (w * 8) * 4 * 64 * 8 + ln * 8;
#pragma unroll
        for (int it = 0; it < 8; it++) {
            bf16x8 af = *(const bf16x8*)&xs[l15][it * 32 + q * 8];
#pragma unroll
            for (int ft = 0; ft < 4; ft++) {
                bf16x8 bf = *((const bf16x8*)(wb + (it * 4 + ft) * 512));
                acc[ft] = __builtin_amdgcn_mfma_f32_16x16x32_bf16(af, bf, acc[ft], 0, 0, 0);
            }
        }

        // Store hp frag-packed (R5 layout). Lane holds h[i=it0+q*4+r][f=ft*16+l15].
        const int jg = it0 >> 5;
        const int q2 = 2 * ((it0 >> 4) & 1) + (q >> 1);
#pragma unroll
        for (int ft = 0; ft < 4; ft++) {
            u16x4 hb;
#pragma unroll
            for (int r = 0; r < 4; r++) hb[r] = f2bf(acc[ft][r]);
            const size_t addr =
                (size_t)((((b * H_ + w) * 32 + jg) * 4 + ft) * 64 + q2 * 16 + l15) * 8 + (q & 1) * 4;
            *((u16x4*)(hp + addr)) = hb;
        }

        // e logits from fp32 acc (x log2e), stored f32 (R5 path).
        float as_v[4], ad_v[4];
#pragma unroll
        for (int ft = 0; ft < 4; ft++) {
            as_v[ft] = a_src[w * F_ + ft * 16 + l15];
            ad_v[ft] = a_dst[w * F_ + ft * 16 + l15];
        }
        float ps[4], pd[4];
#pragma unroll
        for (int r = 0; r < 4; r++) {
            ps[r] = 0.0f; pd[r] = 0.0f;
#pragma unroll
            for (int ft = 0; ft < 4; ft++) {
                ps[r] += acc[ft][r] * as_v[ft];
                pd[r] += acc[ft][r] * ad_v[ft];
            }
        }
#pragma unroll
        for (int off = 1; off <= 8; off <<= 1)
#pragma unroll
            for (int r = 0; r < 4; r++) {
                ps[r] += __shfl_xor(ps[r], off);
                pd[r] += __shfl_xor(pd[r], off);
            }
        float vs = (l15 == 0) ? ps[0] : (l15 == 1) ? ps[1] : (l15 == 2) ? ps[2] : ps[3];
        float vd = (l15 == 0) ? pd[0] : (l15 == 1) ? pd[1] : (l15 == 2) ? pd[2] : pd[3];
        if (l15 < 4) {
            const int i = it0 + q * 4 + l15;
            e_src[(b * H_ + w) * N_ + i] = vs * LOG2E_;
            e_dst[(b * H_ + w) * N_ + i] = vd * LOG2E_;
        }
    }
}

// ---------------------------------------------------------------------------
// Kernel C (R9): fused mask/leaky/exp2 + (P @ h) MFMA + normalize + bias.
// R5 numerics VERBATIM per-wave. R9 occupancy fix WITHOUT register caps:
//   R3 lesson: __launch_bounds__ min-waves=8 caps VGPR at 64 -> 40-reg acc
//   state spills (WRITE_SIZE 407 MB, 131 us). This body needs ~100 free
//   VGPRs; keep (512,4) so the allocator stays at ~52.
//   R0's real occupancy limit was the GRID: 512 blocks / 256 CU = 2/CU =
//   16 waves/CU. New grid: 1024 = 16b x 32 it0-tiles x 2 HEAD-PAIRS; block
//   = 8 waves = 2 heads x 4 j-quarters (8 jg each). Head-split duplicates
//   no hp traffic (heads read disjoint hp), unlike i-splitting.
//   Resources: VGPR 52 <= 64 -> 8 waves/SIMD ok; LDS 20 KB -> 8 blocks;
//   threads 2048/512 -> 4 blocks/CU = 32 waves/CU (2x R0).
//   Combine: sequential 4-pass LDS add (R3-proven logic) per local head.
// ---------------------------------------------------------------------------
__global__ __launch_bounds__(512, 4) void gat_attn_kernel(
    const unsigned int* __restrict__ mask, const unsigned short* __restrict__ hp,
    const float* __restrict__ e_src, const float* __restrict__ e_dst,
    const float* __restrict__ bias, float* __restrict__ out) {
    const int lid   = ((blockIdx.x & 7) << 7) | (blockIdx.x >> 3);  // 1024=8*128, bijective
    const int b     = lid >> 6;
    const int rem   = lid & 63;
    const int it0   = (rem >> 1) * 32;
    const int hpair = rem & 1;
    const int w8  = threadIdx.x >> 6;
    const int h2  = w8 & 1;             // local head (0..1)
    const int jq  = w8 >> 1;            // j-quarter (0..3)
    const int h   = hpair * 2 + h2;     // global head
    const int ln  = threadIdx.x & 63;
    const int l15 = ln & 15;
    const int q   = ln >> 4;

    __shared__ float lds[2][2][5][64][4];   // 20 KB: 2 local heads

    float edv[2];
    edv[0] = e_dst[(b * H_ + h) * N_ + it0 + l15];
    edv[1] = e_dst[(b * H_ + h) * N_ + it0 + 16 + l15];

    const float* es_base          = e_src + (b * H_ + h) * N_;
    const unsigned short* hp_base = hp + (size_t)((b * H_ + h) * 32) * 2048 + ln * 8;
    const unsigned int* mk0       = mask + b * 32 * N_ + it0;

    f32x4 acc[2][4];
    f32x4 accs[2];
#pragma unroll
    for (int mt = 0; mt < 2; mt++) {
#pragma unroll
        for (int ft = 0; ft < 4; ft++) acc[mt][ft] = (f32x4)0.0f;
        accs[mt] = (f32x4)0.0f;
    }

    u16x8 ones_u;
#pragma unroll
    for (int jj = 0; jj < 8; jj++) ones_u[jj] = 0x3F80;   // bf16 1.0
    const bf16x8 ones = __builtin_bit_cast(bf16x8, ones_u);

    for (int jg = jq * 8; jg < jq * 8 + 8; jg++) {
        const unsigned short* hf = hp_base + jg * 2048;
        bf16x8 bfr0 = *((const bf16x8*)(hf + 0 * 512));
        bf16x8 bfr1 = *((const bf16x8*)(hf + 1 * 512));
        bf16x8 bfr2 = *((const bf16x8*)(hf + 2 * 512));
        bf16x8 bfr3 = *((const bf16x8*)(hf + 3 * 512));
        f32x4 e0 = *(const f32x4*)(es_base + jg * 32 + q * 8);
        f32x4 e1 = *(const f32x4*)(es_base + jg * 32 + q * 8 + 4);
        const unsigned m0 = mk0[jg * N_ + l15];
        const unsigned m1 = mk0[jg * N_ + 16 + l15];

        float es8[8] = {e0[0], e0[1], e0[2], e0[3], e1[0], e1[1], e1[2], e1[3]};

        bf16x8 afr[2];
#pragma unroll
        for (int mt = 0; mt < 2; mt++) {
            const unsigned mq = ((mt ? m1 : m0) >> (q * 8)) & 0xffu;
            u32x4 up;
#pragma unroll
            for (int p2 = 0; p2 < 4; p2++) {
                float t0 = edv[mt] + es8[2 * p2];
                float t1 = edv[mt] + es8[2 * p2 + 1];
                t0 = fmaxf(t0, NEG_ * t0);                 // leaky (log2-space)
                t1 = fmaxf(t1, NEG_ * t1);
                float p0 = __builtin_amdgcn_exp2f(t0);
                float p1 = __builtin_amdgcn_exp2f(t1);
                p0 = ((mq >> (2 * p2)) & 1u) ? p0 : 0.0f;
                p1 = ((mq >> (2 * p2 + 1)) & 1u) ? p1 : 0.0f;
                up[p2] = __builtin_amdgcn_perm(__builtin_bit_cast(unsigned, p1),
                                               __builtin_bit_cast(unsigned, p0),
                                               0x07060302u);
            }
            afr[mt] = __builtin_bit_cast(bf16x8, up);
        }
#pragma unroll
        for (int mt = 0; mt < 2; mt++) {
            acc[mt][0] = __builtin_amdgcn_mfma_f32_16x16x32_bf16(afr[mt], bfr0, acc[mt][0], 0, 0, 0);
            acc[mt][1] = __builtin_amdgcn_mfma_f32_16x16x32_bf16(afr[mt], bfr1, acc[mt][1], 0, 0, 0);
            acc[mt][2] = __builtin_amdgcn_mfma_f32_16x16x32_bf16(afr[mt], bfr2, acc[mt][2], 0, 0, 0);
            acc[mt][3] = __builtin_amdgcn_mfma_f32_16x16x32_bf16(afr[mt], bfr3, acc[mt][3], 0, 0, 0);
            accs[mt]   = __builtin_amdgcn_mfma_f32_16x16x32_bf16(afr[mt], ones, accs[mt], 0, 0, 0);
        }
    }

    // 4-way sequential combine into 20KB LDS (per local head).
    if (jq == 3) {
#pragma unroll
        for (int mt = 0; mt < 2; mt++) {
#pragma unroll
            for (int ft = 0; ft < 4; ft++)
                *(f32x4*)&lds[h2][mt][ft][ln][0] = acc[mt][ft];
            *(f32x4*)&lds[h2][mt][4][ln][0] = accs[mt];
        }
    }
    __syncthreads();
    if (jq == 2) {
#pragma unroll
        for (int mt = 0; mt < 2; mt++) {
#pragma unroll
            for (int ft = 0; ft < 4; ft++) {
                f32x4 t = *(const f32x4*)&lds[h2][mt][ft][ln][0];
                *(f32x4*)&lds[h2][mt][ft][ln][0] = t + acc[mt][ft];
            }
            f32x4 ts = *(const f32x4*)&lds[h2][mt][4][ln][0];
            *(f32x4*)&lds[h2][mt][4][ln][0] = ts + accs[mt];
        }
    }
    __syncthreads();
    if (jq == 1) {
#pragma unroll
        for (int mt = 0; mt < 2; mt++) {
#pragma unroll
            for (int ft = 0; ft < 4; ft++) {
                f32x4 t = *(const f32x4*)&lds[h2][mt][ft][ln][0];
                *(f32x4*)&lds[h2][mt][ft][ln][0] = t + acc[mt][ft];
            }
            f32x4 ts = *(const f32x4*)&lds[h2][mt][4][ln][0];
            *(f32x4*)&lds[h2][mt][4][ln][0] = ts + accs[mt];
        }
    }
    __syncthreads();
    if (jq == 0) {
#pragma unroll
        for (int mt = 0; mt < 2; mt++) {
#pragma unroll
            for (int ft = 0; ft < 4; ft++)
                acc[mt][ft] += *(const f32x4*)&lds[h2][mt][ft][ln][0];
            accs[mt] += *(const f32x4*)&lds[h2][mt][4][ln][0];
        }
        float bias_v[4];
#pragma unroll
        for (int ft = 0; ft < 4; ft++) bias_v[ft] = bias[h * F_ + ft * 16 + l15];
#pragma unroll
        for (int mt = 0; mt < 2; mt++) {
            f32x4 rinv;
#pragma unroll
            for (int r = 0; r < 4; r++) rinv[r] = 1.0f / accs[mt][r];
#pragma unroll
            for (int ft = 0; ft < 4; ft++)
#pragma unroll
                for (int r = 0; r < 4; r++) {
                    const int i = it0 + mt * 16 + q * 4 + r;
                    const int c = h * F_ + ft * 16 + l15;
                    out[(size_t)(b * N_ + i) * COUT_ + c] = acc[mt][ft][r] * rinv[r] + bias_v[ft];
                }
        }
    }
}

// ---------------------------------------------------------------------------
// Workspace layout (bytes):
//   [0, 128K)    Wtp  bf16 frag-packed [256][256]
//   [128K, +8M)  hp   bf16 frag-packed [B][H][32][4][64][8]
//   +8M: e_src f32 (256K), e_dst f32 (256K), mask u32 (2M). Total ~10.7 MB.
// ---------------------------------------------------------------------------
extern "C" void kernel_launch(void* const* d_in, const int* in_sizes, int n_in,
                              void* d_out, int out_size, void* d_ws, size_t ws_size,
                              hipStream_t stream) {
    const float* x     = (const float*)d_in[0];
    const float* adj   = (const float*)d_in[1];
    const float* W     = (const float*)d_in[2];
    const float* a_src = (const float*)d_in[3];
    const float* a_dst = (const float*)d_in[4];
    const float* bias  = (const float*)d_in[5];
    float* out = (float*)d_out;

    char* ws = (char*)d_ws;
    unsigned short* Wtp = (unsigned short*)ws;
    unsigned short* hp  = (unsigned short*)(ws + 131072);
    float* e_src        = (float*)(ws + 131072 + 8388608);
    float* e_dst        = (float*)(ws + 131072 + 8388608 + 262144);
    unsigned int* mask  = (unsigned int*)(ws + 131072 + 8388608 + 524288);

    prep_kernel<<<256, 256, 0, stream>>>(W, Wtp);
    stage_kernel<<<5120, 256, 0, stream>>>(adj, x, Wtp, a_src, a_dst, mask, hp, e_src, e_dst);
    gat_attn_kernel<<<1024, 512, 0, stream>>>(mask, hp, e_src, e_dst, bias, out);
}

// Round 5
// 149.046 us; speedup vs baseline: 1.7522x; 1.0153x over previous
//
#include <hip/hip_runtime.h>

// Problem constants
#define B_    16
#define N_    1024
#define DIN_  256
#define H_    4
#define F_    64
#define COUT_ 256
#define NEG_  0.2f
#define LOG2E_ 1.4426950408889634f

typedef __bf16 bf16x8 __attribute__((ext_vector_type(8)));
typedef float  f32x4  __attribute__((ext_vector_type(4)));
typedef unsigned short u16x8 __attribute__((ext_vector_type(8)));
typedef unsigned short u16x4 __attribute__((ext_vector_type(4)));
typedef unsigned int   u32x4 __attribute__((ext_vector_type(4)));

__device__ __forceinline__ unsigned short f2bf(float f) {
    unsigned u = __builtin_bit_cast(unsigned, f);
    u += 0x7fffu + ((u >> 16) & 1u);
    return (unsigned short)(u >> 16);
}

// ---------------------------------------------------------------------------
// Prep: pack W into MFMA-B-frag order Wtp, bf16 (1KB-contiguous frag loads).
// ---------------------------------------------------------------------------
__global__ __launch_bounds__(256) void prep_kernel(
    const float* __restrict__ W, unsigned short* __restrict__ Wtp) {
    const int c = blockIdx.x, k = threadIdx.x;
    const int w = c >> 6, ft = (c >> 4) & 3, l15 = c & 15;
    const int it = k >> 5, q = (k >> 3) & 3, jj = k & 7;
    const int ln = q * 16 + l15;
    Wtp[((((w * 8 + it) * 4 + ft) * 64) + ln) * 8 + jj] = f2bf(W[k * COUT_ + c]);
}

// ---------------------------------------------------------------------------
// Stage kernel (R0-proven, unchanged).
// Part 1 (blocks 0..4095): adj -> transposed bitmask, coalesced.
// Part 2 (blocks 4096..5119): h = x @ W via bf16 MFMA; hp frag-packed;
//   e logits (x log2e) from fp32 acc, stored f32.
// ---------------------------------------------------------------------------
__global__ __launch_bounds__(256, 4) void stage_kernel(
    const float* __restrict__ adj, const float* __restrict__ x,
    const unsigned short* __restrict__ Wtp, const float* __restrict__ a_src,
    const float* __restrict__ a_dst, unsigned int* __restrict__ mask,
    unsigned short* __restrict__ hp, float* __restrict__ e_src,
    float* __restrict__ e_dst) {
    __shared__ unsigned short xs[16][264];   // bf16 bits; padded row stride
    const int w  = threadIdx.x >> 6;
    const int ln = threadIdx.x & 63;

    if (blockIdx.x < 4096) {
        // ---- masker part: 1 row per wave, fully coalesced ----
        const int row = blockIdx.x * 4 + w;          // b*N + i, 0..16383
        const int b = row >> 10, i = row & (N_ - 1);
        const float* ar = adj + (size_t)row * N_ + ln * 4;
#pragma unroll
        for (int c = 0; c < 4; c++) {
            f32x4 v = *(const f32x4*)(ar + c * 256);
            unsigned nib = 0;
#pragma unroll
            for (int e = 0; e < 4; e++)
                nib |= (v[e] > 0.5f) ? (1u << e) : 0u;
            unsigned word = nib << ((ln & 7) * 4);
            word |= __shfl_xor(word, 1);
            word |= __shfl_xor(word, 2);
            word |= __shfl_xor(word, 4);
            if ((ln & 7) == 0) {
                const int jc = c * 8 + (ln >> 3);
                mask[(b * 32 + jc) * N_ + i] = word;
            }
        }
    } else {
        // ---- gat_h part (bf16, R5 numerics, LDS-staged x) ----
        const int blk = blockIdx.x - 4096;
        const int b   = blk & 15;
        const int it0 = (blk >> 4) * 16;
        const int l15 = ln & 15;
        const int q   = ln >> 4;

#pragma unroll
        for (int s = 0; s < 4; s++) {
            const int row = w * 4 + s;
            f32x4 xv = *(const f32x4*)(x + (size_t)(b * N_ + it0 + row) * DIN_ + ln * 4);
            unsigned lo = (unsigned)f2bf(xv[0]) | ((unsigned)f2bf(xv[1]) << 16);
            unsigned hi = (unsigned)f2bf(xv[2]) | ((unsigned)f2bf(xv[3]) << 16);
            unsigned long long hb = (unsigned long long)lo | ((unsigned long long)hi << 32);
            *(unsigned long long*)&xs[row][ln * 4] = hb;
        }
        __syncthreads();

        f32x4 acc[4];
#pragma unroll
        for (int ft = 0; ft < 4; ft++) acc[ft] = (f32x4)0.0f;

        const unsigned short* wb = Wtp + (w * 8) * 4 * 64 * 8 + ln * 8;
#pragma unroll
        for (int it = 0; it < 8; it++) {
            bf16x8 af = *(const bf16x8*)&xs[l15][it * 32 + q * 8];
#pragma unroll
            for (int ft = 0; ft < 4; ft++) {
                bf16x8 bf = *((const bf16x8*)(wb + (it * 4 + ft) * 512));
                acc[ft] = __builtin_amdgcn_mfma_f32_16x16x32_bf16(af, bf, acc[ft], 0, 0, 0);
            }
        }

        const int jg = it0 >> 5;
        const int q2 = 2 * ((it0 >> 4) & 1) + (q >> 1);
#pragma unroll
        for (int ft = 0; ft < 4; ft++) {
            u16x4 hb;
#pragma unroll
            for (int r = 0; r < 4; r++) hb[r] = f2bf(acc[ft][r]);
            const size_t addr =
                (size_t)((((b * H_ + w) * 32 + jg) * 4 + ft) * 64 + q2 * 16 + l15) * 8 + (q & 1) * 4;
            *((u16x4*)(hp + addr)) = hb;
        }

        float as_v[4], ad_v[4];
#pragma unroll
        for (int ft = 0; ft < 4; ft++) {
            as_v[ft] = a_src[w * F_ + ft * 16 + l15];
            ad_v[ft] = a_dst[w * F_ + ft * 16 + l15];
        }
        float ps[4], pd[4];
#pragma unroll
        for (int r = 0; r < 4; r++) {
            ps[r] = 0.0f; pd[r] = 0.0f;
#pragma unroll
            for (int ft = 0; ft < 4; ft++) {
                ps[r] += acc[ft][r] * as_v[ft];
                pd[r] += acc[ft][r] * ad_v[ft];
            }
        }
#pragma unroll
        for (int off = 1; off <= 8; off <<= 1)
#pragma unroll
            for (int r = 0; r < 4; r++) {
                ps[r] += __shfl_xor(ps[r], off);
                pd[r] += __shfl_xor(pd[r], off);
            }
        float vs = (l15 == 0) ? ps[0] : (l15 == 1) ? ps[1] : (l15 == 2) ? ps[2] : ps[3];
        float vd = (l15 == 0) ? pd[0] : (l15 == 1) ? pd[1] : (l15 == 2) ? pd[2] : pd[3];
        if (l15 < 4) {
            const int i = it0 + q * 4 + l15;
            e_src[(b * H_ + w) * N_ + i] = vs * LOG2E_;
            e_dst[(b * H_ + w) * N_ + i] = vd * LOG2E_;
        }
    }
}

// ---------------------------------------------------------------------------
// Kernel C (R10): fused mask/leaky/exp2 + (P @ h) MFMA + normalize + bias.
// R5 numerics; R0 shape (512 blk x 512 thr, 4h x 2jh, 40KB combine).
// R10 anti-serialization changes (R1/R4 falsified hp-tier & occupancy):
//   (a) e_src (16KB, 4 heads) + mask tile (4KB) staged in LDS once per
//       block -> per-jg global loads 8 -> 4 (hp only); es/mask become
//       broadcast conflict-free ds_reads.
//   (b) hp register double-buffer: unrolled jg loop issues jg+1's 4 hp
//       loads BEFORE jg's VALU+MFMA in program order -> L2/L3 latency
//       hides under ~400cy of compute instead of serializing per phase.
// LDS 40+16+4 = 60KB -> 2 blocks/CU (same occupancy as R0). VGPR ~104
// (<=128 cap at (512,4) -> no spill; R3 lesson).
// ---------------------------------------------------------------------------
__global__ __launch_bounds__(512, 4) void gat_attn_kernel(
    const unsigned int* __restrict__ mask, const unsigned short* __restrict__ hp,
    const float* __restrict__ e_src, const float* __restrict__ e_dst,
    const float* __restrict__ bias, float* __restrict__ out) {
    const int lid = ((blockIdx.x & 7) << 6) | (blockIdx.x >> 3);  // XCD swizzle
    const int b   = lid >> 5;
    const int it0 = (lid & 31) * 32;
    const int w8  = threadIdx.x >> 6;
    const int h   = w8 & 3;             // head
    const int jh  = w8 >> 2;            // j-half
    const int ln  = threadIdx.x & 63;
    const int l15 = ln & 15;
    const int q   = ln >> 4;

    __shared__ float lds[H_][2][5][64][4];   // 40 KB: acc[2][4] + accs[2]
    __shared__ float es_s[H_][N_];           // 16 KB: e_src all 4 heads
    __shared__ unsigned mk_s[32][32];        // 4 KB: mask words [jg][i-in-tile]

    // ---- cooperative staging of es + mask tiles ----
    {
        const int tid = threadIdx.x;
#pragma unroll
        for (int p = 0; p < 2; p++) {
            const int c  = p * 512 + tid;        // 0..1023 f32x4-chunks
            const int h_ = c >> 8;
            const int of = (c & 255) * 4;
            *(f32x4*)&es_s[h_][of] =
                *(const f32x4*)(e_src + (size_t)(b * H_ + h_) * N_ + of);
        }
        if (tid < 256) {
            const int jc = tid >> 3;
            const int i4 = (tid & 7) * 4;
            *(u32x4*)&mk_s[jc][i4] =
                *(const u32x4*)(mask + (size_t)(b * 32 + jc) * N_ + it0 + i4);
        }
    }

    float edv[2];
    edv[0] = e_dst[(b * H_ + h) * N_ + it0 + l15];
    edv[1] = e_dst[(b * H_ + h) * N_ + it0 + 16 + l15];

    const unsigned short* hp_base = hp + (size_t)((b * H_ + h) * 32) * 2048 + ln * 8;

    f32x4 acc[2][4];
    f32x4 accs[2];
#pragma unroll
    for (int mt = 0; mt < 2; mt++) {
#pragma unroll
        for (int ft = 0; ft < 4; ft++) acc[mt][ft] = (f32x4)0.0f;
        accs[mt] = (f32x4)0.0f;
    }

    u16x8 ones_u;
#pragma unroll
    for (int jj = 0; jj < 8; jj++) ones_u[jj] = 0x3F80;   // bf16 1.0
    const bf16x8 ones = __builtin_bit_cast(bf16x8, ones_u);

    __syncthreads();   // es_s/mk_s ready

    // ---- hp register double-buffer: prefetch jg0 ----
    const unsigned short* hf0 = hp_base + (size_t)(jh * 16) * 2048;
    bf16x8 nb0 = *((const bf16x8*)(hf0 + 0 * 512));
    bf16x8 nb1 = *((const bf16x8*)(hf0 + 1 * 512));
    bf16x8 nb2 = *((const bf16x8*)(hf0 + 2 * 512));
    bf16x8 nb3 = *((const bf16x8*)(hf0 + 3 * 512));

#pragma unroll
    for (int t = 0; t < 16; t++) {
        const int jg = jh * 16 + t;
        const bf16x8 cb0 = nb0, cb1 = nb1, cb2 = nb2, cb3 = nb3;
        if (t < 15) {   // issue next-jg hp loads before this jg's compute
            const unsigned short* hfn = hp_base + (size_t)(jg + 1) * 2048;
            nb0 = *((const bf16x8*)(hfn + 0 * 512));
            nb1 = *((const bf16x8*)(hfn + 1 * 512));
            nb2 = *((const bf16x8*)(hfn + 2 * 512));
            nb3 = *((const bf16x8*)(hfn + 3 * 512));
        }

        f32x4 e0 = *(const f32x4*)&es_s[h][jg * 32 + q * 8];
        f32x4 e1 = *(const f32x4*)&es_s[h][jg * 32 + q * 8 + 4];
        const unsigned m0 = mk_s[jg][l15];
        const unsigned m1 = mk_s[jg][16 + l15];

        float es8[8] = {e0[0], e0[1], e0[2], e0[3], e1[0], e1[1], e1[2], e1[3]};

        bf16x8 afr[2];
#pragma unroll
        for (int mt = 0; mt < 2; mt++) {
            const unsigned mq = ((mt ? m1 : m0) >> (q * 8)) & 0xffu;
            u32x4 up;
#pragma unroll
            for (int p2 = 0; p2 < 4; p2++) {
                float t0 = edv[mt] + es8[2 * p2];
                float t1 = edv[mt] + es8[2 * p2 + 1];
                t0 = fmaxf(t0, NEG_ * t0);                 // leaky (log2-space)
                t1 = fmaxf(t1, NEG_ * t1);
                float p0 = __builtin_amdgcn_exp2f(t0);
                float p1 = __builtin_amdgcn_exp2f(t1);
                p0 = ((mq >> (2 * p2)) & 1u) ? p0 : 0.0f;
                p1 = ((mq >> (2 * p2 + 1)) & 1u) ? p1 : 0.0f;
                up[p2] = __builtin_amdgcn_perm(__builtin_bit_cast(unsigned, p1),
                                               __builtin_bit_cast(unsigned, p0),
                                               0x07060302u);
            }
            afr[mt] = __builtin_bit_cast(bf16x8, up);
        }
#pragma unroll
        for (int mt = 0; mt < 2; mt++) {
            acc[mt][0] = __builtin_amdgcn_mfma_f32_16x16x32_bf16(afr[mt], cb0, acc[mt][0], 0, 0, 0);
            acc[mt][1] = __builtin_amdgcn_mfma_f32_16x16x32_bf16(afr[mt], cb1, acc[mt][1], 0, 0, 0);
            acc[mt][2] = __builtin_amdgcn_mfma_f32_16x16x32_bf16(afr[mt], cb2, acc[mt][2], 0, 0, 0);
            acc[mt][3] = __builtin_amdgcn_mfma_f32_16x16x32_bf16(afr[mt], cb3, acc[mt][3], 0, 0, 0);
            accs[mt]   = __builtin_amdgcn_mfma_f32_16x16x32_bf16(afr[mt], ones, accs[mt], 0, 0, 0);
        }
    }

    // Cross-j-half combine via LDS.
    if (jh == 1) {
#pragma unroll
        for (int mt = 0; mt < 2; mt++) {
#pragma unroll
            for (int ft = 0; ft < 4; ft++)
                *(f32x4*)&lds[h][mt][ft][ln][0] = acc[mt][ft];
            *(f32x4*)&lds[h][mt][4][ln][0] = accs[mt];
        }
    }
    __syncthreads();
    if (jh == 0) {
#pragma unroll
        for (int mt = 0; mt < 2; mt++) {
#pragma unroll
            for (int ft = 0; ft < 4; ft++)
                acc[mt][ft] += *(const f32x4*)&lds[h][mt][ft][ln][0];
            accs[mt] += *(const f32x4*)&lds[h][mt][4][ln][0];
        }
        float bias_v[4];
#pragma unroll
        for (int ft = 0; ft < 4; ft++) bias_v[ft] = bias[h * F_ + ft * 16 + l15];
#pragma unroll
        for (int mt = 0; mt < 2; mt++) {
            f32x4 rinv;
#pragma unroll
            for (int r = 0; r < 4; r++) rinv[r] = 1.0f / accs[mt][r];
#pragma unroll
            for (int ft = 0; ft < 4; ft++)
#pragma unroll
                for (int r = 0; r < 4; r++) {
                    const int i = it0 + mt * 16 + q * 4 + r;
                    const int c = h * F_ + ft * 16 + l15;
                    out[(size_t)(b * N_ + i) * COUT_ + c] = acc[mt][ft][r] * rinv[r] + bias_v[ft];
                }
        }
    }
}

// ---------------------------------------------------------------------------
// Workspace layout (bytes):
//   [0, 128K)    Wtp  bf16 frag-packed [256][256]
//   [128K, +8M)  hp   bf16 frag-packed [B][H][32][4][64][8]
//   +8M: e_src f32 (256K), e_dst f32 (256K), mask u32 (2M). Total ~10.7 MB.
// ---------------------------------------------------------------------------
extern "C" void kernel_launch(void* const* d_in, const int* in_sizes, int n_in,
                              void* d_out, int out_size, void* d_ws, size_t ws_size,
                              hipStream_t stream) {
    const float* x     = (const float*)d_in[0];
    const float* adj   = (const float*)d_in[1];
    const float* W     = (const float*)d_in[2];
    const float* a_src = (const float*)d_in[3];
    const float* a_dst = (const float*)d_in[4];
    const float* bias  = (const float*)d_in[5];
    float* out = (float*)d_out;

    char* ws = (char*)d_ws;
    unsigned short* Wtp = (unsigned short*)ws;
    unsigned short* hp  = (unsigned short*)(ws + 131072);
    float* e_src        = (float*)(ws + 131072 + 8388608);
    float* e_dst        = (float*)(ws + 131072 + 8388608 + 262144);
    unsigned int* mask  = (unsigned int*)(ws + 131072 + 8388608 + 524288);

    prep_kernel<<<256, 256, 0, stream>>>(W, Wtp);
    stage_kernel<<<5120, 256, 0, stream>>>(adj, x, Wtp, a_src, a_dst, mask, hp, e_src, e_dst);
    gat_attn_kernel<<<512, 512, 0, stream>>>(mask, hp, e_src, e_dst, bias, out);
}

// Round 6
// 145.221 us; speedup vs baseline: 1.7984x; 1.0263x over previous
//
#include <hip/hip_runtime.h>

// Problem constants
#define B_    16
#define N_    1024
#define DIN_  256
#define H_    4
#define F_    64
#define COUT_ 256
#define NEG_  0.2f
#define LOG2E_ 1.4426950408889634f

typedef __bf16 bf16x8 __attribute__((ext_vector_type(8)));
typedef float  f32x4  __attribute__((ext_vector_type(4)));
typedef unsigned short u16x8 __attribute__((ext_vector_type(8)));
typedef unsigned short u16x4 __attribute__((ext_vector_type(4)));
typedef unsigned int   u32x4 __attribute__((ext_vector_type(4)));

__device__ __forceinline__ unsigned short f2bf(float f) {
    unsigned u = __builtin_bit_cast(unsigned, f);
    u += 0x7fffu + ((u >> 16) & 1u);
    return (unsigned short)(u >> 16);
}

// ---------------------------------------------------------------------------
// Prep: pack W into MFMA-B-frag order Wtp, bf16 (1KB-contiguous frag loads).
// ---------------------------------------------------------------------------
__global__ __launch_bounds__(256) void prep_kernel(
    const float* __restrict__ W, unsigned short* __restrict__ Wtp) {
    const int c = blockIdx.x, k = threadIdx.x;
    const int w = c >> 6, ft = (c >> 4) & 3, l15 = c & 15;
    const int it = k >> 5, q = (k >> 3) & 3, jj = k & 7;
    const int ln = q * 16 + l15;
    Wtp[((((w * 8 + it) * 4 + ft) * 64) + ln) * 8 + jj] = f2bf(W[k * COUT_ + c]);
}

// ---------------------------------------------------------------------------
// Stage kernel — R11 anti-latency restructure.
// R5 counters: stage 42us, HBM 16.6%, VALU 9.8%, MFMA 1.8%, Occ 51% =>
// latency-bound at 3-4x its ~13us memory floor. Old masker: 4096 tiny
// blocks, each wave 4 loads -> full latency eaten once per block, stream
// drains between block generations; gat_h tail-serialized after masker.
// New: 512 masker blocks (0..511), 8 rows/wave with 2-DEEP ROW PIPELINE
// (prefetch row r+1's 4x f32x4 before processing row r) -> every wave
// keeps >=4KB in flight, latency hidden, masker stream-bound. gat_h =
// blocks 512..1535 (body unchanged). 1536 blocks = 6/CU, all co-resident
// -> MFMA overlaps the adj stream from t=0. Per-row mask logic and all
// gat_h numerics byte-identical.
// ---------------------------------------------------------------------------
__global__ __launch_bounds__(256, 4) void stage_kernel(
    const float* __restrict__ adj, const float* __restrict__ x,
    const unsigned short* __restrict__ Wtp, const float* __restrict__ a_src,
    const float* __restrict__ a_dst, unsigned int* __restrict__ mask,
    unsigned short* __restrict__ hp, float* __restrict__ e_src,
    float* __restrict__ e_dst) {
    __shared__ unsigned short xs[16][264];   // bf16 bits; padded row stride
    const int w  = threadIdx.x >> 6;
    const int ln = threadIdx.x & 63;

    if (blockIdx.x < 512) {
        // ---- masker: 32 rows/block, 8 rows/wave, 2-deep pipeline ----
        const int row0 = blockIdx.x * 32 + w * 8;    // b*N + i
        const float* ar = adj + (size_t)row0 * N_ + ln * 4;

        f32x4 cur[4];
#pragma unroll
        for (int c = 0; c < 4; c++) cur[c] = *(const f32x4*)(ar + c * 256);

#pragma unroll
        for (int r = 0; r < 8; r++) {
            f32x4 nxt[4];
            if (r < 7) {   // issue next row's loads BEFORE this row's work
#pragma unroll
                for (int c = 0; c < 4; c++)
                    nxt[c] = *(const f32x4*)(ar + (size_t)(r + 1) * N_ + c * 256);
            }
            const int row = row0 + r;
            const int b = row >> 10, i = row & (N_ - 1);
#pragma unroll
            for (int c = 0; c < 4; c++) {
                unsigned nib = 0;
#pragma unroll
                for (int e = 0; e < 4; e++)
                    nib |= (cur[c][e] > 0.5f) ? (1u << e) : 0u;
                unsigned word = nib << ((ln & 7) * 4);
                word |= __shfl_xor(word, 1);
                word |= __shfl_xor(word, 2);
                word |= __shfl_xor(word, 4);
                if ((ln & 7) == 0) {
                    const int jc = c * 8 + (ln >> 3);
                    mask[(b * 32 + jc) * N_ + i] = word;
                }
            }
            if (r < 7) {
#pragma unroll
                for (int c = 0; c < 4; c++) cur[c] = nxt[c];
            }
        }
    } else {
        // ---- gat_h part (bf16, R5 numerics, LDS-staged x; unchanged) ----
        const int blk = blockIdx.x - 512;
        const int b   = blk & 15;
        const int it0 = (blk >> 4) * 16;
        const int l15 = ln & 15;
        const int q   = ln >> 4;

#pragma unroll
        for (int s = 0; s < 4; s++) {
            const int row = w * 4 + s;
            f32x4 xv = *(const f32x4*)(x + (size_t)(b * N_ + it0 + row) * DIN_ + ln * 4);
            unsigned lo = (unsigned)f2bf(xv[0]) | ((unsigned)f2bf(xv[1]) << 16);
            unsigned hi = (unsigned)f2bf(xv[2]) | ((unsigned)f2bf(xv[3]) << 16);
            unsigned long long hb = (unsigned long long)lo | ((unsigned long long)hi << 32);
            *(unsigned long long*)&xs[row][ln * 4] = hb;
        }
        __syncthreads();

        f32x4 acc[4];
#pragma unroll
        for (int ft = 0; ft < 4; ft++) acc[ft] = (f32x4)0.0f;

        const unsigned short* wb = Wtp + (w * 8) * 4 * 64 * 8 + ln * 8;
#pragma unroll
        for (int it = 0; it < 8; it++) {
            bf16x8 af = *(const bf16x8*)&xs[l15][it * 32 + q * 8];
#pragma unroll
            for (int ft = 0; ft < 4; ft++) {
                bf16x8 bf = *((const bf16x8*)(wb + (it * 4 + ft) * 512));
                acc[ft] = __builtin_amdgcn_mfma_f32_16x16x32_bf16(af, bf, acc[ft], 0, 0, 0);
            }
        }

        const int jg = it0 >> 5;
        const int q2 = 2 * ((it0 >> 4) & 1) + (q >> 1);
#pragma unroll
        for (int ft = 0; ft < 4; ft++) {
            u16x4 hb;
#pragma unroll
            for (int r = 0; r < 4; r++) hb[r] = f2bf(acc[ft][r]);
            const size_t addr =
                (size_t)((((b * H_ + w) * 32 + jg) * 4 + ft) * 64 + q2 * 16 + l15) * 8 + (q & 1) * 4;
            *((u16x4*)(hp + addr)) = hb;
        }

        float as_v[4], ad_v[4];
#pragma unroll
        for (int ft = 0; ft < 4; ft++) {
            as_v[ft] = a_src[w * F_ + ft * 16 + l15];
            ad_v[ft] = a_dst[w * F_ + ft * 16 + l15];
        }
        float ps[4], pd[4];
#pragma unroll
        for (int r = 0; r < 4; r++) {
            ps[r] = 0.0f; pd[r] = 0.0f;
#pragma unroll
            for (int ft = 0; ft < 4; ft++) {
                ps[r] += acc[ft][r] * as_v[ft];
                pd[r] += acc[ft][r] * ad_v[ft];
            }
        }
#pragma unroll
        for (int off = 1; off <= 8; off <<= 1)
#pragma unroll
            for (int r = 0; r < 4; r++) {
                ps[r] += __shfl_xor(ps[r], off);
                pd[r] += __shfl_xor(pd[r], off);
            }
        float vs = (l15 == 0) ? ps[0] : (l15 == 1) ? ps[1] : (l15 == 2) ? ps[2] : ps[3];
        float vd = (l15 == 0) ? pd[0] : (l15 == 1) ? pd[1] : (l15 == 2) ? pd[2] : pd[3];
        if (l15 < 4) {
            const int i = it0 + q * 4 + l15;
            e_src[(b * H_ + w) * N_ + i] = vs * LOG2E_;
            e_dst[(b * H_ + w) * N_ + i] = vd * LOG2E_;
        }
    }
}

// ---------------------------------------------------------------------------
// Kernel C (R10 attn, kept): fused mask/leaky/exp2 + (P @ h) MFMA +
// normalize + bias. es/mask LDS-staged, hp register double-buffered.
// ---------------------------------------------------------------------------
__global__ __launch_bounds__(512, 4) void gat_attn_kernel(
    const unsigned int* __restrict__ mask, const unsigned short* __restrict__ hp,
    const float* __restrict__ e_src, const float* __restrict__ e_dst,
    const float* __restrict__ bias, float* __restrict__ out) {
    const int lid = ((blockIdx.x & 7) << 6) | (blockIdx.x >> 3);  // XCD swizzle
    const int b   = lid >> 5;
    const int it0 = (lid & 31) * 32;
    const int w8  = threadIdx.x >> 6;
    const int h   = w8 & 3;             // head
    const int jh  = w8 >> 2;            // j-half
    const int ln  = threadIdx.x & 63;
    const int l15 = ln & 15;
    const int q   = ln >> 4;

    __shared__ float lds[H_][2][5][64][4];   // 40 KB: acc[2][4] + accs[2]
    __shared__ float es_s[H_][N_];           // 16 KB: e_src all 4 heads
    __shared__ unsigned mk_s[32][32];        // 4 KB: mask words [jg][i-in-tile]

    // ---- cooperative staging of es + mask tiles ----
    {
        const int tid = threadIdx.x;
#pragma unroll
        for (int p = 0; p < 2; p++) {
            const int c  = p * 512 + tid;        // 0..1023 f32x4-chunks
            const int h_ = c >> 8;
            const int of = (c & 255) * 4;
            *(f32x4*)&es_s[h_][of] =
                *(const f32x4*)(e_src + (size_t)(b * H_ + h_) * N_ + of);
        }
        if (tid < 256) {
            const int jc = tid >> 3;
            const int i4 = (tid & 7) * 4;
            *(u32x4*)&mk_s[jc][i4] =
                *(const u32x4*)(mask + (size_t)(b * 32 + jc) * N_ + it0 + i4);
        }
    }

    float edv[2];
    edv[0] = e_dst[(b * H_ + h) * N_ + it0 + l15];
    edv[1] = e_dst[(b * H_ + h) * N_ + it0 + 16 + l15];

    const unsigned short* hp_base = hp + (size_t)((b * H_ + h) * 32) * 2048 + ln * 8;

    f32x4 acc[2][4];
    f32x4 accs[2];
#pragma unroll
    for (int mt = 0; mt < 2; mt++) {
#pragma unroll
        for (int ft = 0; ft < 4; ft++) acc[mt][ft] = (f32x4)0.0f;
        accs[mt] = (f32x4)0.0f;
    }

    u16x8 ones_u;
#pragma unroll
    for (int jj = 0; jj < 8; jj++) ones_u[jj] = 0x3F80;   // bf16 1.0
    const bf16x8 ones = __builtin_bit_cast(bf16x8, ones_u);

    __syncthreads();   // es_s/mk_s ready

    // ---- hp register double-buffer: prefetch jg0 ----
    const unsigned short* hf0 = hp_base + (size_t)(jh * 16) * 2048;
    bf16x8 nb0 = *((const bf16x8*)(hf0 + 0 * 512));
    bf16x8 nb1 = *((const bf16x8*)(hf0 + 1 * 512));
    bf16x8 nb2 = *((const bf16x8*)(hf0 + 2 * 512));
    bf16x8 nb3 = *((const bf16x8*)(hf0 + 3 * 512));

#pragma unroll
    for (int t = 0; t < 16; t++) {
        const int jg = jh * 16 + t;
        const bf16x8 cb0 = nb0, cb1 = nb1, cb2 = nb2, cb3 = nb3;
        if (t < 15) {   // issue next-jg hp loads before this jg's compute
            const unsigned short* hfn = hp_base + (size_t)(jg + 1) * 2048;
            nb0 = *((const bf16x8*)(hfn + 0 * 512));
            nb1 = *((const bf16x8*)(hfn + 1 * 512));
            nb2 = *((const bf16x8*)(hfn + 2 * 512));
            nb3 = *((const bf16x8*)(hfn + 3 * 512));
        }

        f32x4 e0 = *(const f32x4*)&es_s[h][jg * 32 + q * 8];
        f32x4 e1 = *(const f32x4*)&es_s[h][jg * 32 + q * 8 + 4];
        const unsigned m0 = mk_s[jg][l15];
        const unsigned m1 = mk_s[jg][16 + l15];

        float es8[8] = {e0[0], e0[1], e0[2], e0[3], e1[0], e1[1], e1[2], e1[3]};

        bf16x8 afr[2];
#pragma unroll
        for (int mt = 0; mt < 2; mt++) {
            const unsigned mq = ((mt ? m1 : m0) >> (q * 8)) & 0xffu;
            u32x4 up;
#pragma unroll
            for (int p2 = 0; p2 < 4; p2++) {
                float t0 = edv[mt] + es8[2 * p2];
                float t1 = edv[mt] + es8[2 * p2 + 1];
                t0 = fmaxf(t0, NEG_ * t0);                 // leaky (log2-space)
                t1 = fmaxf(t1, NEG_ * t1);
                float p0 = __builtin_amdgcn_exp2f(t0);
                float p1 = __builtin_amdgcn_exp2f(t1);
                p0 = ((mq >> (2 * p2)) & 1u) ? p0 : 0.0f;
                p1 = ((mq >> (2 * p2 + 1)) & 1u) ? p1 : 0.0f;
                up[p2] = __builtin_amdgcn_perm(__builtin_bit_cast(unsigned, p1),
                                               __builtin_bit_cast(unsigned, p0),
                                               0x07060302u);
            }
            afr[mt] = __builtin_bit_cast(bf16x8, up);
        }
#pragma unroll
        for (int mt = 0; mt < 2; mt++) {
            acc[mt][0] = __builtin_amdgcn_mfma_f32_16x16x32_bf16(afr[mt], cb0, acc[mt][0], 0, 0, 0);
            acc[mt][1] = __builtin_amdgcn_mfma_f32_16x16x32_bf16(afr[mt], cb1, acc[mt][1], 0, 0, 0);
            acc[mt][2] = __builtin_amdgcn_mfma_f32_16x16x32_bf16(afr[mt], cb2, acc[mt][2], 0, 0, 0);
            acc[mt][3] = __builtin_amdgcn_mfma_f32_16x16x32_bf16(afr[mt], cb3, acc[mt][3], 0, 0, 0);
            accs[mt]   = __builtin_amdgcn_mfma_f32_16x16x32_bf16(afr[mt], ones, accs[mt], 0, 0, 0);
        }
    }

    // Cross-j-half combine via LDS.
    if (jh == 1) {
#pragma unroll
        for (int mt = 0; mt < 2; mt++) {
#pragma unroll
            for (int ft = 0; ft < 4; ft++)
                *(f32x4*)&lds[h][mt][ft][ln][0] = acc[mt][ft];
            *(f32x4*)&lds[h][mt][4][ln][0] = accs[mt];
        }
    }
    __syncthreads();
    if (jh == 0) {
#pragma unroll
        for (int mt = 0; mt < 2; mt++) {
#pragma unroll
            for (int ft = 0; ft < 4; ft++)
                acc[mt][ft] += *(const f32x4*)&lds[h][mt][ft][ln][0];
            accs[mt] += *(const f32x4*)&lds[h][mt][4][ln][0];
        }
        float bias_v[4];
#pragma unroll
        for (int ft = 0; ft < 4; ft++) bias_v[ft] = bias[h * F_ + ft * 16 + l15];
#pragma unroll
        for (int mt = 0; mt < 2; mt++) {
            f32x4 rinv;
#pragma unroll
            for (int r = 0; r < 4; r++) rinv[r] = 1.0f / accs[mt][r];
#pragma unroll
            for (int ft = 0; ft < 4; ft++)
#pragma unroll
                for (int r = 0; r < 4; r++) {
                    const int i = it0 + mt * 16 + q * 4 + r;
                    const int c = h * F_ + ft * 16 + l15;
                    out[(size_t)(b * N_ + i) * COUT_ + c] = acc[mt][ft][r] * rinv[r] + bias_v[ft];
                }
        }
    }
}

// ---------------------------------------------------------------------------
// Workspace layout (bytes):
//   [0, 128K)    Wtp  bf16 frag-packed [256][256]
//   [128K, +8M)  hp   bf16 frag-packed [B][H][32][4][64][8]
//   +8M: e_src f32 (256K), e_dst f32 (256K), mask u32 (2M). Total ~10.7 MB.
// ---------------------------------------------------------------------------
extern "C" void kernel_launch(void* const* d_in, const int* in_sizes, int n_in,
                              void* d_out, int out_size, void* d_ws, size_t ws_size,
                              hipStream_t stream) {
    const float* x     = (const float*)d_in[0];
    const float* adj   = (const float*)d_in[1];
    const float* W     = (const float*)d_in[2];
    const float* a_src = (const float*)d_in[3];
    const float* a_dst = (const float*)d_in[4];
    const float* bias  = (const float*)d_in[5];
    float* out = (float*)d_out;

    char* ws = (char*)d_ws;
    unsigned short* Wtp = (unsigned short*)ws;
    unsigned short* hp  = (unsigned short*)(ws + 131072);
    float* e_src        = (float*)(ws + 131072 + 8388608);
    float* e_dst        = (float*)(ws + 131072 + 8388608 + 262144);
    unsigned int* mask  = (unsigned int*)(ws + 131072 + 8388608 + 524288);

    prep_kernel<<<256, 256, 0, stream>>>(W, Wtp);
    stage_kernel<<<1536, 256, 0, stream>>>(adj, x, Wtp, a_src, a_dst, mask, hp, e_src, e_dst);
    gat_attn_kernel<<<512, 512, 0, stream>>>(mask, hp, e_src, e_dst, bias, out);
}

// Round 7
// 142.501 us; speedup vs baseline: 1.8327x; 1.0191x over previous
//
#include <hip/hip_runtime.h>

// Problem constants
#define B_    16
#define N_    1024
#define DIN_  256
#define H_    4
#define F_    64
#define COUT_ 256
#define NEG_  0.2f
#define LOG2E_ 1.4426950408889634f

typedef __bf16 bf16x8 __attribute__((ext_vector_type(8)));
typedef float  f32x4  __attribute__((ext_vector_type(4)));
typedef unsigned short u16x8 __attribute__((ext_vector_type(8)));
typedef unsigned short u16x4 __attribute__((ext_vector_type(4)));
typedef unsigned int   u32x4 __attribute__((ext_vector_type(4)));

__device__ __forceinline__ unsigned short f2bf(float f) {
    unsigned u = __builtin_bit_cast(unsigned, f);
    u += 0x7fffu + ((u >> 16) & 1u);
    return (unsigned short)(u >> 16);
}

// ---------------------------------------------------------------------------
// Prep: pack W into MFMA-B-frag order Wtp, bf16 (1KB-contiguous frag loads).
// ---------------------------------------------------------------------------
__global__ __launch_bounds__(256) void prep_kernel(
    const float* __restrict__ W, unsigned short* __restrict__ Wtp) {
    const int c = blockIdx.x, k = threadIdx.x;
    const int w = c >> 6, ft = (c >> 4) & 3, l15 = c & 15;
    const int it = k >> 5, q = (k >> 3) & 3, jj = k & 7;
    const int ln = q * 16 + l15;
    Wtp[((((w * 8 + it) * 4 + ft) * 64) + ln) * 8 + jj] = f2bf(W[k * COUT_ + c]);
}

// ---------------------------------------------------------------------------
// Stage kernel — R12 ballot masker.
// R11 post-mortem: 512-block masker = 2 waves/SIMD, pipeline couldn't cover
// latency; and the real cost was never the loads (R5: HBM 16%) but (a) 4
// chains of 3 DEPENDENT ds_bpermute shuffles per row and (b) 32 single-
// dword stores scattered at 4KB stride (j-major mask transpose).
// R12: __ballot produces 64 j-bits/SGPR-pair in 1 inst -> zero DS ops;
// mask stored I-MAJOR [b][i][32w] -> one coalesced 128B store per row.
// Bit routing: word jg, bit (8e+t) <-> j = jg*32 + 4t + e (attn unpack
// adjusted to match; gating semantics exact). Masker: 4096 blocks,
// 1 row/wave (R5 occupancy). gat_h (blocks 4096..5119) unchanged.
// ---------------------------------------------------------------------------
__global__ __launch_bounds__(256, 4) void stage_kernel(
    const float* __restrict__ adj, const float* __restrict__ x,
    const unsigned short* __restrict__ Wtp, const float* __restrict__ a_src,
    const float* __restrict__ a_dst, unsigned int* __restrict__ mask,
    unsigned short* __restrict__ hp, float* __restrict__ e_src,
    float* __restrict__ e_dst) {
    __shared__ unsigned short xs[16][264];   // bf16 bits; padded row stride
    const int w  = threadIdx.x >> 6;
    const int ln = threadIdx.x & 63;

    if (blockIdx.x < 4096) {
        // ---- masker: 1 row/wave, ballot-based, coalesced i-major store ----
        const int row = blockIdx.x * 4 + w;          // b*N + i, 0..16383
        const float* ar = adj + (size_t)row * N_ + ln * 4;

        f32x4 v0 = *(const f32x4*)(ar);
        f32x4 v1 = *(const f32x4*)(ar + 256);
        f32x4 v2 = *(const f32x4*)(ar + 512);
        f32x4 v3 = *(const f32x4*)(ar + 768);

        // 16 ballots: bal[c][e] bit ln <-> adj[i][c*256 + ln*4 + e] > 0.5
        unsigned long long bal[4][4];
#pragma unroll
        for (int e = 0; e < 4; e++) {
            bal[0][e] = __ballot(v0[e] > 0.5f);
            bal[1][e] = __ballot(v1[e] > 0.5f);
            bal[2][e] = __ballot(v2[e] > 0.5f);
            bal[3][e] = __ballot(v3[e] > 0.5f);
        }

        // Lane ln<32 assembles word jg=ln: c=ln>>3, byte k=ln&7 of each
        // bal[c][e] -> word bit (8e+t) <-> j = jg*32 + 4t + e.
        const int c_ = (ln >> 3) & 3;
        const int sh = (ln & 7) * 8;
        unsigned wd = 0;
#pragma unroll
        for (int e = 0; e < 4; e++) {
            unsigned long long be = (c_ == 0) ? bal[0][e]
                                  : (c_ == 1) ? bal[1][e]
                                  : (c_ == 2) ? bal[2][e] : bal[3][e];
            wd |= ((unsigned)((be >> sh) & 0xffull)) << (8 * e);
        }
        if (ln < 32)
            mask[(size_t)row * 32 + ln] = wd;
    } else {
        // ---- gat_h part (bf16, R5 numerics, LDS-staged x; unchanged) ----
        const int blk = blockIdx.x - 4096;
        const int b   = blk & 15;
        const int it0 = (blk >> 4) * 16;
        const int l15 = ln & 15;
        const int q   = ln >> 4;

#pragma unroll
        for (int s = 0; s < 4; s++) {
            const int row = w * 4 + s;
            f32x4 xv = *(const f32x4*)(x + (size_t)(b * N_ + it0 + row) * DIN_ + ln * 4);
            unsigned lo = (unsigned)f2bf(xv[0]) | ((unsigned)f2bf(xv[1]) << 16);
            unsigned hi = (unsigned)f2bf(xv[2]) | ((unsigned)f2bf(xv[3]) << 16);
            unsigned long long hb = (unsigned long long)lo | ((unsigned long long)hi << 32);
            *(unsigned long long*)&xs[row][ln * 4] = hb;
        }
        __syncthreads();

        f32x4 acc[4];
#pragma unroll
        for (int ft = 0; ft < 4; ft++) acc[ft] = (f32x4)0.0f;

        const unsigned short* wb = Wtp + (w * 8) * 4 * 64 * 8 + ln * 8;
#pragma unroll
        for (int it = 0; it < 8; it++) {
            bf16x8 af = *(const bf16x8*)&xs[l15][it * 32 + q * 8];
#pragma unroll
            for (int ft = 0; ft < 4; ft++) {
                bf16x8 bf = *((const bf16x8*)(wb + (it * 4 + ft) * 512));
                acc[ft] = __builtin_amdgcn_mfma_f32_16x16x32_bf16(af, bf, acc[ft], 0, 0, 0);
            }
        }

        const int jg = it0 >> 5;
        const int q2 = 2 * ((it0 >> 4) & 1) + (q >> 1);
#pragma unroll
        for (int ft = 0; ft < 4; ft++) {
            u16x4 hb;
#pragma unroll
            for (int r = 0; r < 4; r++) hb[r] = f2bf(acc[ft][r]);
            const size_t addr =
                (size_t)((((b * H_ + w) * 32 + jg) * 4 + ft) * 64 + q2 * 16 + l15) * 8 + (q & 1) * 4;
            *((u16x4*)(hp + addr)) = hb;
        }

        float as_v[4], ad_v[4];
#pragma unroll
        for (int ft = 0; ft < 4; ft++) {
            as_v[ft] = a_src[w * F_ + ft * 16 + l15];
            ad_v[ft] = a_dst[w * F_ + ft * 16 + l15];
        }
        float ps[4], pd[4];
#pragma unroll
        for (int r = 0; r < 4; r++) {
            ps[r] = 0.0f; pd[r] = 0.0f;
#pragma unroll
            for (int ft = 0; ft < 4; ft++) {
                ps[r] += acc[ft][r] * as_v[ft];
                pd[r] += acc[ft][r] * ad_v[ft];
            }
        }
#pragma unroll
        for (int off = 1; off <= 8; off <<= 1)
#pragma unroll
            for (int r = 0; r < 4; r++) {
                ps[r] += __shfl_xor(ps[r], off);
                pd[r] += __shfl_xor(pd[r], off);
            }
        float vs = (l15 == 0) ? ps[0] : (l15 == 1) ? ps[1] : (l15 == 2) ? ps[2] : ps[3];
        float vd = (l15 == 0) ? pd[0] : (l15 == 1) ? pd[1] : (l15 == 2) ? pd[2] : pd[3];
        if (l15 < 4) {
            const int i = it0 + q * 4 + l15;
            e_src[(b * H_ + w) * N_ + i] = vs * LOG2E_;
            e_dst[(b * H_ + w) * N_ + i] = vd * LOG2E_;
        }
    }
}

// ---------------------------------------------------------------------------
// Kernel C (R12 attn = R10 body + i-major mask tile).
// mk_s now [32 i-rows][37] (pad -> conflict-free reads); staged as one
// contiguous 4KB global read. Gate bits follow the ballot permutation:
// w = word >> (2q); p0 bits {0,16,1,17}[p2], p1 bits {8,24,9,25}[p2].
// Identical gating semantics to R0 (same float compare upstream).
// ---------------------------------------------------------------------------
__global__ __launch_bounds__(512, 4) void gat_attn_kernel(
    const unsigned int* __restrict__ mask, const unsigned short* __restrict__ hp,
    const float* __restrict__ e_src, const float* __restrict__ e_dst,
    const float* __restrict__ bias, float* __restrict__ out) {
    const int lid = ((blockIdx.x & 7) << 6) | (blockIdx.x >> 3);  // XCD swizzle
    const int b   = lid >> 5;
    const int it0 = (lid & 31) * 32;
    const int w8  = threadIdx.x >> 6;
    const int h   = w8 & 3;             // head
    const int jh  = w8 >> 2;            // j-half
    const int ln  = threadIdx.x & 63;
    const int l15 = ln & 15;
    const int q   = ln >> 4;

    __shared__ float lds[H_][2][5][64][4];   // 40 KB: acc[2][4] + accs[2]
    __shared__ float es_s[H_][N_];           // 16 KB: e_src all 4 heads
    __shared__ unsigned mk_s[32][37];        // ~4.6 KB: mask words [i'][jg], padded

    // ---- cooperative staging of es + mask tiles ----
    {
        const int tid = threadIdx.x;
#pragma unroll
        for (int p = 0; p < 2; p++) {
            const int c  = p * 512 + tid;        // 0..1023 f32x4-chunks
            const int h_ = c >> 8;
            const int of = (c & 255) * 4;
            *(f32x4*)&es_s[h_][of] =
                *(const f32x4*)(e_src + (size_t)(b * H_ + h_) * N_ + of);
        }
        if (tid < 256) {
            const int ii  = tid >> 3;            // i-row in tile
            const int jc4 = (tid & 7) * 4;       // word group
            u32x4 mv = *(const u32x4*)(mask + ((size_t)(b * N_ + it0 + ii)) * 32 + jc4);
            mk_s[ii][jc4 + 0] = mv[0];
            mk_s[ii][jc4 + 1] = mv[1];
            mk_s[ii][jc4 + 2] = mv[2];
            mk_s[ii][jc4 + 3] = mv[3];
        }
    }

    float edv[2];
    edv[0] = e_dst[(b * H_ + h) * N_ + it0 + l15];
    edv[1] = e_dst[(b * H_ + h) * N_ + it0 + 16 + l15];

    const unsigned short* hp_base = hp + (size_t)((b * H_ + h) * 32) * 2048 + ln * 8;

    f32x4 acc[2][4];
    f32x4 accs[2];
#pragma unroll
    for (int mt = 0; mt < 2; mt++) {
#pragma unroll
        for (int ft = 0; ft < 4; ft++) acc[mt][ft] = (f32x4)0.0f;
        accs[mt] = (f32x4)0.0f;
    }

    u16x8 ones_u;
#pragma unroll
    for (int jj = 0; jj < 8; jj++) ones_u[jj] = 0x3F80;   // bf16 1.0
    const bf16x8 ones = __builtin_bit_cast(bf16x8, ones_u);

    __syncthreads();   // es_s/mk_s ready

    // ---- hp register double-buffer: prefetch jg0 ----
    const unsigned short* hf0 = hp_base + (size_t)(jh * 16) * 2048;
    bf16x8 nb0 = *((const bf16x8*)(hf0 + 0 * 512));
    bf16x8 nb1 = *((const bf16x8*)(hf0 + 1 * 512));
    bf16x8 nb2 = *((const bf16x8*)(hf0 + 2 * 512));
    bf16x8 nb3 = *((const bf16x8*)(hf0 + 3 * 512));

    const int bp0[4] = {0, 16, 1, 17};
    const int bp1[4] = {8, 24, 9, 25};

#pragma unroll
    for (int t = 0; t < 16; t++) {
        const int jg = jh * 16 + t;
        const bf16x8 cb0 = nb0, cb1 = nb1, cb2 = nb2, cb3 = nb3;
        if (t < 15) {   // issue next-jg hp loads before this jg's compute
            const unsigned short* hfn = hp_base + (size_t)(jg + 1) * 2048;
            nb0 = *((const bf16x8*)(hfn + 0 * 512));
            nb1 = *((const bf16x8*)(hfn + 1 * 512));
            nb2 = *((const bf16x8*)(hfn + 2 * 512));
            nb3 = *((const bf16x8*)(hfn + 3 * 512));
        }

        f32x4 e0 = *(const f32x4*)&es_s[h][jg * 32 + q * 8];
        f32x4 e1 = *(const f32x4*)&es_s[h][jg * 32 + q * 8 + 4];
        const unsigned w0 = mk_s[l15][jg] >> (2 * q);
        const unsigned w1 = mk_s[16 + l15][jg] >> (2 * q);

        float es8[8] = {e0[0], e0[1], e0[2], e0[3], e1[0], e1[1], e1[2], e1[3]};

        bf16x8 afr[2];
#pragma unroll
        for (int mt = 0; mt < 2; mt++) {
            const unsigned mw = mt ? w1 : w0;
            u32x4 up;
#pragma unroll
            for (int p2 = 0; p2 < 4; p2++) {
                float t0 = edv[mt] + es8[2 * p2];
                float t1 = edv[mt] + es8[2 * p2 + 1];
                t0 = fmaxf(t0, NEG_ * t0);                 // leaky (log2-space)
                t1 = fmaxf(t1, NEG_ * t1);
                float p0 = __builtin_amdgcn_exp2f(t0);
                float p1 = __builtin_amdgcn_exp2f(t1);
                p0 = ((mw >> bp0[p2]) & 1u) ? p0 : 0.0f;
                p1 = ((mw >> bp1[p2]) & 1u) ? p1 : 0.0f;
                up[p2] = __builtin_amdgcn_perm(__builtin_bit_cast(unsigned, p1),
                                               __builtin_bit_cast(unsigned, p0),
                                               0x07060302u);
            }
            afr[mt] = __builtin_bit_cast(bf16x8, up);
        }
#pragma unroll
        for (int mt = 0; mt < 2; mt++) {
            acc[mt][0] = __builtin_amdgcn_mfma_f32_16x16x32_bf16(afr[mt], cb0, acc[mt][0], 0, 0, 0);
            acc[mt][1] = __builtin_amdgcn_mfma_f32_16x16x32_bf16(afr[mt], cb1, acc[mt][1], 0, 0, 0);
            acc[mt][2] = __builtin_amdgcn_mfma_f32_16x16x32_bf16(afr[mt], cb2, acc[mt][2], 0, 0, 0);
            acc[mt][3] = __builtin_amdgcn_mfma_f32_16x16x32_bf16(afr[mt], cb3, acc[mt][3], 0, 0, 0);
            accs[mt]   = __builtin_amdgcn_mfma_f32_16x16x32_bf16(afr[mt], ones, accs[mt], 0, 0, 0);
        }
    }

    // Cross-j-half combine via LDS.
    if (jh == 1) {
#pragma unroll
        for (int mt = 0; mt < 2; mt++) {
#pragma unroll
            for (int ft = 0; ft < 4; ft++)
                *(f32x4*)&lds[h][mt][ft][ln][0] = acc[mt][ft];
            *(f32x4*)&lds[h][mt][4][ln][0] = accs[mt];
        }
    }
    __syncthreads();
    if (jh == 0) {
#pragma unroll
        for (int mt = 0; mt < 2; mt++) {
#pragma unroll
            for (int ft = 0; ft < 4; ft++)
                acc[mt][ft] += *(const f32x4*)&lds[h][mt][ft][ln][0];
            accs[mt] += *(const f32x4*)&lds[h][mt][4][ln][0];
        }
        float bias_v[4];
#pragma unroll
        for (int ft = 0; ft < 4; ft++) bias_v[ft] = bias[h * F_ + ft * 16 + l15];
#pragma unroll
        for (int mt = 0; mt < 2; mt++) {
            f32x4 rinv;
#pragma unroll
            for (int r = 0; r < 4; r++) rinv[r] = 1.0f / accs[mt][r];
#pragma unroll
            for (int ft = 0; ft < 4; ft++)
#pragma unroll
                for (int r = 0; r < 4; r++) {
                    const int i = it0 + mt * 16 + q * 4 + r;
                    const int c = h * F_ + ft * 16 + l15;
                    out[(size_t)(b * N_ + i) * COUT_ + c] = acc[mt][ft][r] * rinv[r] + bias_v[ft];
                }
        }
    }
}

// ---------------------------------------------------------------------------
// Workspace layout (bytes):
//   [0, 128K)    Wtp  bf16 frag-packed [256][256]
//   [128K, +8M)  hp   bf16 frag-packed [B][H][32][4][64][8]
//   +8M: e_src f32 (256K), e_dst f32 (256K), mask u32 i-major [B][N][32] (2M).
// ---------------------------------------------------------------------------
extern "C" void kernel_launch(void* const* d_in, const int* in_sizes, int n_in,
                              void* d_out, int out_size, void* d_ws, size_t ws_size,
                              hipStream_t stream) {
    const float* x     = (const float*)d_in[0];
    const float* adj   = (const float*)d_in[1];
    const float* W     = (const float*)d_in[2];
    const float* a_src = (const float*)d_in[3];
    const float* a_dst = (const float*)d_in[4];
    const float* bias  = (const float*)d_in[5];
    float* out = (float*)d_out;

    char* ws = (char*)d_ws;
    unsigned short* Wtp = (unsigned short*)ws;
    unsigned short* hp  = (unsigned short*)(ws + 131072);
    float* e_src        = (float*)(ws + 131072 + 8388608);
    float* e_dst        = (float*)(ws + 131072 + 8388608 + 262144);
    unsigned int* mask  = (unsigned int*)(ws + 131072 + 8388608 + 524288);

    prep_kernel<<<256, 256, 0, stream>>>(W, Wtp);
    stage_kernel<<<5120, 256, 0, stream>>>(adj, x, Wtp, a_src, a_dst, mask, hp, e_src, e_dst);
    gat_attn_kernel<<<512, 512, 0, stream>>>(mask, hp, e_src, e_dst, bias, out);
}